// Round 5
// baseline (94.446 us; speedup 1.0000x reference)
//
#include <hip/hip_runtime.h>
#include <stdint.h>

#define DEVFN __device__ __forceinline__

typedef __attribute__((ext_vector_type(8))) short s16x8;
typedef __attribute__((ext_vector_type(4))) float f32x4;

DEVFN float bf2f(uint16_t u) {
  union { uint32_t i; float f; } v; v.i = ((uint32_t)u) << 16; return v.f;
}
DEVFN uint16_t f2bf(float f) {
  union { float f; uint32_t i; } v; v.f = f;
  uint32_t u = v.i;
  return (uint16_t)((u + 0x7FFFu + ((u >> 16) & 1u)) >> 16);
}

DEVFN void gload_lds16(const void* g, void* l) {
  __builtin_amdgcn_global_load_lds(
      (const __attribute__((address_space(1))) uint32_t*)g,
      (__attribute__((address_space(3))) uint32_t*)l, 16, 0, 0);
}

// ---------------------------------------------------------------------------
// Fused prep: blocks 0..2047  : x -> Xh (hi) + XR = BN(AvgPool4) hi ONLY
//             blocks 2048..5119: Wk/Wv -> Wkvi (hi, ROW-INTERLEAVED), Wp -> Wph
// Wkvi row layout: head h (0..31): rows h*64..h*64+31 = Wk rows h*32..,
//                  rows h*64+32..h*64+63 = Wv rows h*32.. ; one BN=64 GEMM
//                  tile = [K_h | V_h] -> per-block KV Gram contraction.
// ---------------------------------------------------------------------------
__global__ __launch_bounds__(256)
void prep_kernel(const float* __restrict__ x,
                 const float* __restrict__ bn_g, const float* __restrict__ bn_b,
                 const float* __restrict__ bn_m, const float* __restrict__ bn_v,
                 const float* __restrict__ Wk, const float* __restrict__ Wv,
                 const float* __restrict__ Wp,
                 uint16_t* __restrict__ Xh,
                 uint16_t* __restrict__ XRh,
                 uint16_t* __restrict__ Wkvi,
                 uint16_t* __restrict__ Wph)
{
  const int t = threadIdx.x;
  const int bid = blockIdx.x;
  if (bid < 2048) {
    const int prow = bid;                    // pooled row: b*512 + mm
    const int c0 = t * 4;
    const size_t xbase = (size_t)prow * 4096 + c0;   // x row prow*4
    float s[4] = {0.f, 0.f, 0.f, 0.f};
#pragma unroll
    for (int r = 0; r < 4; ++r) {
      const float4 w = *(const float4*)(x + xbase + (size_t)r * 1024);
      const float vv[4] = { w.x, w.y, w.z, w.w };
      uint64_t wh = 0;
#pragma unroll
      for (int j = 0; j < 4; ++j) {
        wh |= ((uint64_t)f2bf(vv[j])) << (16 * j);
        s[j] += vv[j];
      }
      *(uint64_t*)(Xh + xbase + (size_t)r * 1024) = wh;
    }
    uint64_t wh = 0;
#pragma unroll
    for (int j = 0; j < 4; ++j) {
      const int c = c0 + j;
      const float y = (s[j] * 0.25f - bn_m[c]) / sqrtf(bn_v[c] + 1e-6f) * bn_g[c] + bn_b[c];
      wh |= ((uint64_t)f2bf(y)) << (16 * j);
    }
    *(uint64_t*)(XRh + (size_t)prow * 1024 + c0) = wh;
  } else {
    const int wb = bid - 2048;               // 0..3071
    const int which = wb >> 10;
    const int i = (wb & 1023) * 256 + t;     // float4 index
    const float* src = (which == 0) ? Wk : (which == 1) ? Wv : Wp;
    const float4 v = ((const float4*)src)[i];
    const float vv[4] = { v.x, v.y, v.z, v.w };
    uint64_t wh = 0;
#pragma unroll
    for (int j = 0; j < 4; ++j)
      wh |= ((uint64_t)f2bf(vv[j])) << (16 * j);
    if (which == 2) {
      ((uint64_t*)Wph)[i] = wh;
    } else {
      const int row  = i >> 8;               // 0..1023 source row
      const int col4 = i & 255;
      const int nrow = ((row >> 5) << 6) + which * 32 + (row & 31);
      ((uint64_t*)Wkvi)[(size_t)nrow * 256 + col4] = wh;
    }
  }
}

// ---------------------------------------------------------------------------
// NT GEMM — r2 champion structure (single-buffer, 2-barrier, BK=128).
// C[m,n] = sum_k A[m,k]*B[n,k].
//   SMALLM=false: BM=128, waves 2x2, acc[4][4], LDS 64KB -> 2 blocks/CU.
//   SMALLM=true : BM=64,  waves 1x4, acc[4][2], LDS 48KB.
// LDS row = 256B (16 x 16B slots); phys slot s at row r holds src slot
// s ^ (r&7); ds_read same involution -> conflict-free (r2 measured).
// EPI: 1 = bf16 hi Cb0, 2 = fp32 C32 + bias
// BATCHB: B advances N*K per rows_per_batch rows of A. AMODA: A row &1023.
// ---------------------------------------------------------------------------
template<bool BATCHB, bool AMODA, int EPI, bool SMALLM>
__global__ __launch_bounds__(256, 2)
void gemm_nt(const uint16_t* __restrict__ A0,
             const uint16_t* __restrict__ B0,
             float* __restrict__ C32, uint16_t* __restrict__ Cb0,
             const float* __restrict__ bias,
             int M, int N, int K, int rows_per_batch)
{
  constexpr int BM = SMALLM ? 64 : 128, BN = 128, BK = 128;
  constexpr int WCN = SMALLM ? 4 : 2;         // waves along N
  constexpr int WNW = BN / WCN;               // per-wave N width (32 or 64)
  constexpr int NREP = WNW / 16;              // 2 or 4
  constexpr int APASS = SMALLM ? 4 : 8;       // A staging passes (4KB each)
  constexpr int BPASS = 8;                    // B staging passes
  __shared__ uint16_t sA[BM * BK];
  __shared__ uint16_t sB[BN * BK];

  const int t = threadIdx.x;
  const int lane = t & 63;
  const int wave = t >> 6;
  const int wr = wave / WCN, wc = wave % WCN;
  const int fq = lane >> 4, fr = lane & 15;

  // T1: XCD-chunked swizzle (gridDim.x divisible by 8 for all our grids)
  const int nwg = gridDim.x;
  const int cpx = nwg >> 3;
  const int orig = blockIdx.x;
  const int swz = (orig & 7) * cpx + (orig >> 3);
  const int nbx = N >> 7;
  const int bm = (swz / nbx) * BM;
  const int bn = (swz % nbx) * BN;

  const uint16_t* Ap = A0;
  const uint16_t* Bp = B0;
  if (BATCHB)
    Bp += (size_t)(bm / rows_per_batch) * (size_t)N * (size_t)K;

  f32x4 acc[4][NREP];
#pragma unroll
  for (int m = 0; m < 4; ++m)
#pragma unroll
    for (int n = 0; n < NREP; ++n) acc[m][n] = (f32x4)0.0f;

  const int nkt = K >> 7;
  for (int kt = 0; kt < nkt; ++kt) {
    __syncthreads();
#pragma unroll
    for (int i = 0; i < APASS; ++i) {
      const int X = t * 16 + i * 4096;          // linear LDS byte dest
      const int r = X >> 8;                     // row (256B per row)
      const int g = ((X >> 4) & 15) ^ (r & 7);  // pre-swizzled source slot
      const int kcol = (kt << 7) + g * 8;
      const int arow = AMODA ? ((bm + r) & 1023) : (bm + r);
      gload_lds16(Ap + (size_t)arow * K + kcol, (char*)(&sA[0]) + X);
    }
#pragma unroll
    for (int i = 0; i < BPASS; ++i) {
      const int X = t * 16 + i * 4096;
      const int r = X >> 8;
      const int g = ((X >> 4) & 15) ^ (r & 7);
      const int kcol = (kt << 7) + g * 8;
      gload_lds16(Bp + (size_t)(bn + r) * K + kcol, (char*)(&sB[0]) + X);
    }
    __syncthreads();
#pragma unroll
    for (int ks = 0; ks < 4; ++ks) {
      s16x8 av[4], bv[NREP];
#pragma unroll
      for (int m = 0; m < 4; ++m) {
        const int ra = wr * 64 + m * 16 + fr;
        const int offA = ra * 256 + ((((ks << 2) + fq) ^ (ra & 7)) << 4);
        av[m] = *(const s16x8*)((const char*)(&sA[0]) + offA);
      }
#pragma unroll
      for (int n = 0; n < NREP; ++n) {
        const int rb = wc * WNW + n * 16 + fr;
        const int offB = rb * 256 + ((((ks << 2) + fq) ^ (rb & 7)) << 4);
        bv[n] = *(const s16x8*)((const char*)(&sB[0]) + offB);
      }
#pragma unroll
      for (int m = 0; m < 4; ++m)
#pragma unroll
        for (int n = 0; n < NREP; ++n)
          acc[m][n] = __builtin_amdgcn_mfma_f32_16x16x32_bf16(
              av[m], bv[n], acc[m][n], 0, 0, 0);
    }
  }

  // epilogue: C/D layout col = lane&15, row = (lane>>4)*4 + reg (m89/m91)
#pragma unroll
  for (int m = 0; m < 4; ++m) {
#pragma unroll
    for (int n = 0; n < NREP; ++n) {
#pragma unroll
      for (int j = 0; j < 4; ++j) {
        const int row = bm + wr * 64 + m * 16 + fq * 4 + j;
        const int col = bn + wc * WNW + n * 16 + fr;
        const size_t idx = (size_t)row * N + col;
        float v = acc[m][n][j];
        if constexpr (EPI == 1) {
          Cb0[idx] = f2bf(v);
        } else {
          C32[idx] = v + bias[col];
        }
      }
    }
  }
}

// ---------------------------------------------------------------------------
// Fused KV GEMM (r5): C = XRh @ Wkvi^T at BM=128, BN=64, BK=128, full K.
// Grid 16x32 = 512 blocks -> 2/CU, nkt=8 (r2-validated drain economics).
// Block tile = head bnI's [K(cols 0-31) | V(cols 32-63)] over 128 pooled
// rows = 2 ch-chunks of 64. Epilogue: dump fp32 C to LDS (union over
// sA/sB), contract part[bh][ch][f][e] = sum_64rows K[m,f]*V[m,e].
// K,V never rounded to bf16 (r1-proven numerics). Replaces GEMM2+kv1:
// saves 16MB KVcat read + 12MB write + one dispatch.
// ---------------------------------------------------------------------------
__global__ __launch_bounds__(256, 2)
void gemm_kv(const uint16_t* __restrict__ A,   // XRh [2048][1024]
             const uint16_t* __restrict__ B,   // Wkvi [2048][1024]
             float* __restrict__ part)         // [128 bh][8 ch][32][32]
{
  constexpr int BM = 128, BN = 64, BK = 128;
  __shared__ union {
    struct { uint16_t a[BM * BK]; uint16_t b[BN * BK]; } s;   // 32KB + 16KB
    float c[BM][BN];                                          // 32KB
  } sm;

  const int t = threadIdx.x;
  const int lane = t & 63;
  const int wave = t >> 6;                  // 2x2 waves
  const int wr = wave >> 1, wc = wave & 1;
  const int fq = lane >> 4, fr = lane & 15;

  const int nwg = gridDim.x;                // 512
  const int cpx = nwg >> 3;
  const int orig = blockIdx.x;
  const int swz = (orig & 7) * cpx + (orig >> 3);
  const int bmI = swz >> 5;                 // 0..15
  const int bnI = swz & 31;                 // 0..31 = head
  const int bm = bmI * BM;
  const int bn = bnI * BN;

  f32x4 acc[4][2];
#pragma unroll
  for (int m = 0; m < 4; ++m)
#pragma unroll
    for (int n = 0; n < 2; ++n) acc[m][n] = (f32x4)0.0f;

  for (int kt = 0; kt < 8; ++kt) {
    __syncthreads();
#pragma unroll
    for (int i = 0; i < 8; ++i) {           // A: 32KB = 8 x 4KB passes
      const int X = t * 16 + i * 4096;
      const int r = X >> 8;                 // row (256B per row)
      const int g = ((X >> 4) & 15) ^ (r & 7);
      const int kcol = (kt << 7) + g * 8;
      gload_lds16(A + (size_t)(bm + r) * 1024 + kcol, (char*)(&sm.s.a[0]) + X);
    }
#pragma unroll
    for (int i = 0; i < 4; ++i) {           // B: 16KB = 4 x 4KB passes
      const int X = t * 16 + i * 4096;
      const int r = X >> 8;
      const int g = ((X >> 4) & 15) ^ (r & 7);
      const int kcol = (kt << 7) + g * 8;
      gload_lds16(B + (size_t)(bn + r) * 1024 + kcol, (char*)(&sm.s.b[0]) + X);
    }
    __syncthreads();
#pragma unroll
    for (int ks = 0; ks < 4; ++ks) {
      s16x8 av[4], bv[2];
#pragma unroll
      for (int m = 0; m < 4; ++m) {
        const int ra = wr * 64 + m * 16 + fr;
        const int offA = ra * 256 + ((((ks << 2) + fq) ^ (ra & 7)) << 4);
        av[m] = *(const s16x8*)((const char*)(&sm.s.a[0]) + offA);
      }
#pragma unroll
      for (int n = 0; n < 2; ++n) {
        const int rb = wc * 32 + n * 16 + fr;
        const int offB = rb * 256 + ((((ks << 2) + fq) ^ (rb & 7)) << 4);
        bv[n] = *(const s16x8*)((const char*)(&sm.s.b[0]) + offB);
      }
#pragma unroll
      for (int m = 0; m < 4; ++m)
#pragma unroll
        for (int n = 0; n < 2; ++n)
          acc[m][n] = __builtin_amdgcn_mfma_f32_16x16x32_bf16(
              av[m], bv[n], acc[m][n], 0, 0, 0);
    }
  }

  // --- epilogue: dump fp32 C tile to LDS, contract K^T V over 2x64 rows ---
  __syncthreads();                          // all ds_reads of s.a/s.b done
#pragma unroll
  for (int m = 0; m < 4; ++m)
#pragma unroll
    for (int n = 0; n < 2; ++n)
#pragma unroll
      for (int j = 0; j < 4; ++j) {
        const int row = wr * 64 + m * 16 + fq * 4 + j;
        const int col = wc * 32 + n * 16 + fr;
        sm.c[row][col] = acc[m][n][j];
      }
  __syncthreads();

  // thread -> (chs, f, 8 e's): 2*32*4 = 256 assignments, one per thread
  const int chs = t >> 7;                   // which 64-row chunk
  const int f  = (t >> 2) & 31;
  const int e0 = (t & 3) * 8;
  f32x4 a0 = (f32x4)0.0f, a1 = (f32x4)0.0f;
#pragma unroll 8
  for (int mm = 0; mm < 64; ++mm) {
    const int m = chs * 64 + mm;
    const float kf = sm.c[m][f];
    const f32x4 v0 = *(const f32x4*)&sm.c[m][32 + e0];
    const f32x4 v1 = *(const f32x4*)&sm.c[m][36 + e0];
    a0 += v0 * kf;
    a1 += v1 * kf;
  }
  const int b = bmI >> 2, ch = (bmI & 3) * 2 + chs;
  const int h = bnI;
  float* o = part + (((size_t)(b * 32 + h) * 8 + ch) * 32 + f) * 32 + e0;
  *(f32x4*)o = a0;
  *(f32x4*)(o + 4) = a1;
}

// ---------------------------------------------------------------------------
// t_kernel (kv2 fused): KV[b,h] = scale * sum_ch part[bh*8+ch];
// Tt[b][c][h*32+e] = sum_f KV[b,h][f,e] * Wq[h*32+f, c]   (bf16 hi out)
// grid: 512 blocks = (b, h, c-chunk of 256); 256 threads = one c each.
// ---------------------------------------------------------------------------
__global__ __launch_bounds__(256)
void t_kernel(const float* __restrict__ part, const float* __restrict__ Wq,
              uint16_t* __restrict__ Tth)
{
  const int bid = blockIdx.x;        // b*128 + h*4 + cc
  const int b = bid >> 7, h = (bid >> 2) & 31, cc = bid & 3;
  const int bh = b * 32 + h;
  const int t = threadIdx.x;
  __shared__ float sKV[32][32];      // [f][e]
  {
    const int f = t >> 3, e0 = (t & 7) * 4;
    f32x4 a = (f32x4)0.0f;
#pragma unroll
    for (int ch = 0; ch < 8; ++ch)
      a += *(const f32x4*)(part + ((size_t)(bh * 8 + ch) * 32 + f) * 32 + e0);
    a *= 0.17677669529663687f;       // 1/sqrt(32)
    *(f32x4*)&sKV[f][e0] = a;
  }
  __syncthreads();
  const int c = cc * 256 + t;
  f32x4 acc[8];
#pragma unroll
  for (int i = 0; i < 8; ++i) acc[i] = (f32x4)0.0f;
  const float* wqp = Wq + (size_t)(h * 32) * 1024 + c;
#pragma unroll 8
  for (int f = 0; f < 32; ++f) {
    const float wq = wqp[(size_t)f * 1024];
#pragma unroll
    for (int i = 0; i < 8; ++i) {
      const f32x4 kv = *(const f32x4*)&sKV[f][i * 4];
      acc[i] += kv * wq;
    }
  }
  const size_t o = (((size_t)b << 10) + c) * 1024 + h * 32;
#pragma unroll
  for (int i = 0; i < 8; ++i) {
    uint64_t wh = 0;
#pragma unroll
    for (int j = 0; j < 4; ++j)
      wh |= ((uint64_t)f2bf(acc[i][j])) << (16 * j);
    *(uint64_t*)(Tth + o + i * 4) = wh;
  }
}

// ---------------------------------------------------------------------------
extern "C" void kernel_launch(void* const* d_in, const int* in_sizes, int n_in,
                              void* d_out, int out_size, void* d_ws, size_t ws_size,
                              hipStream_t stream)
{
  const float* x   = (const float*)d_in[0];
  const float* Wq  = (const float*)d_in[1];
  const float* Wk  = (const float*)d_in[2];
  const float* Wv  = (const float*)d_in[3];
  const float* Wp  = (const float*)d_in[4];
  const float* bp  = (const float*)d_in[5];
  const float* bng = (const float*)d_in[6];
  const float* bnb = (const float*)d_in[7];
  const float* bnm = (const float*)d_in[8];
  const float* bnv = (const float*)d_in[9];
  float* out = (float*)d_out;

  char* ws = (char*)d_ws;
  size_t off = 0;
  auto alloc = [&](size_t bytes) {
    char* p = ws + off;
    off += (bytes + 255) & ~(size_t)255;
    return p;
  };
  uint16_t* Xh   = (uint16_t*)alloc((size_t)8192 * 1024 * 2);       // 16MB
  uint16_t* XRh  = (uint16_t*)alloc((size_t)2048 * 1024 * 2);       // 4MB
  uint16_t* Wkvi = (uint16_t*)alloc((size_t)2048 * 1024 * 2);       // 4MB
  uint16_t* Wph  = (uint16_t*)alloc((size_t)1024 * 1024 * 2);       // 2MB
  uint16_t* Tth  = (uint16_t*)alloc((size_t)4096 * 1024 * 2);       // 8MB
  uint16_t* Gh   = (uint16_t*)alloc((size_t)4096 * 1024 * 2);       // 8MB
  // overlay: KV partials (4MB) live only gemm_kv -> t_kernel, before the
  // G-GEMM writes Gh
  float* KVpart = (float*)Gh;

  // 1) fused prep: x split (hi) + XR pool/BN (hi) + weight splits (hi,
  //    Wk/Wv row-interleaved for the fused KV GEMM)
  prep_kernel<<<5120, 256, 0, stream>>>(x, bng, bnb, bnm, bnv, Wk, Wv, Wp,
                                        Xh, XRh, Wkvi, Wph);
  // 2) fused [K|V] GEMM + per-block K^T V Gram contraction (replaces
  //    GEMM2 + kv1; r2 drain economics: BM=128, BK=128, 2 blocks/CU)
  gemm_kv<<<512, 256, 0, stream>>>(XRh, Wkvi, KVpart);
  // 3) Tt = (blockdiag(KV)^T Wq)^T, bf16 hi
  t_kernel<<<512, 256, 0, stream>>>(KVpart, Wq, Tth);
  // 4) G[b] = Wph @ Tt[b]^T (hh only), bf16 out, BM=64 -> 512 blocks
  gemm_nt<true, true, 1, true><<<512, 256, 0, stream>>>(
      Wph, Tth, nullptr, Gh, nullptr,
      4096, 1024, 1024, 1024);
  // 5) out = Xh @ G[b]^T + bp (hh only), fp32 out, BM=128 -> 512 blocks
  gemm_nt<true, false, 2, false><<<512, 256, 0, stream>>>(
      Xh, Gh, out, nullptr, bp,
      8192, 1024, 1024, 2048);
}

// Round 6
// 85.467 us; speedup vs baseline: 1.1051x; 1.1051x over previous
//
#include <hip/hip_runtime.h>
#include <stdint.h>

#define DEVFN __device__ __forceinline__

typedef __attribute__((ext_vector_type(8))) short s16x8;
typedef __attribute__((ext_vector_type(4))) float f32x4;

DEVFN float bf2f(uint16_t u) {
  union { uint32_t i; float f; } v; v.i = ((uint32_t)u) << 16; return v.f;
}
DEVFN uint16_t f2bf(float f) {
  union { float f; uint32_t i; } v; v.f = f;
  uint32_t u = v.i;
  return (uint16_t)((u + 0x7FFFu + ((u >> 16) & 1u)) >> 16);
}

DEVFN void gload_lds16(const void* g, void* l) {
  __builtin_amdgcn_global_load_lds(
      (const __attribute__((address_space(1))) uint32_t*)g,
      (__attribute__((address_space(3))) uint32_t*)l, 16, 0, 0);
}

// ---------------------------------------------------------------------------
// Fused prep: blocks 0..2047  : x -> Xh (hi) + XR = BN(AvgPool4) hi ONLY
//             blocks 2048..5119: Wk/Wv -> Wkvh (hi), Wp -> Wph (hi)
// ---------------------------------------------------------------------------
__global__ __launch_bounds__(256)
void prep_kernel(const float* __restrict__ x,
                 const float* __restrict__ bn_g, const float* __restrict__ bn_b,
                 const float* __restrict__ bn_m, const float* __restrict__ bn_v,
                 const float* __restrict__ Wk, const float* __restrict__ Wv,
                 const float* __restrict__ Wp,
                 uint16_t* __restrict__ Xh,
                 uint16_t* __restrict__ XRh,
                 uint16_t* __restrict__ Wkvh,
                 uint16_t* __restrict__ Wph)
{
  const int t = threadIdx.x;
  const int bid = blockIdx.x;
  if (bid < 2048) {
    const int prow = bid;                    // pooled row: b*512 + mm
    const int c0 = t * 4;
    const size_t xbase = (size_t)prow * 4096 + c0;   // x row prow*4
    float s[4] = {0.f, 0.f, 0.f, 0.f};
#pragma unroll
    for (int r = 0; r < 4; ++r) {
      const float4 w = *(const float4*)(x + xbase + (size_t)r * 1024);
      const float vv[4] = { w.x, w.y, w.z, w.w };
      uint64_t wh = 0;
#pragma unroll
      for (int j = 0; j < 4; ++j) {
        wh |= ((uint64_t)f2bf(vv[j])) << (16 * j);
        s[j] += vv[j];
      }
      *(uint64_t*)(Xh + xbase + (size_t)r * 1024) = wh;
    }
    uint64_t wh = 0;
#pragma unroll
    for (int j = 0; j < 4; ++j) {
      const int c = c0 + j;
      const float y = (s[j] * 0.25f - bn_m[c]) / sqrtf(bn_v[c] + 1e-6f) * bn_g[c] + bn_b[c];
      wh |= ((uint64_t)f2bf(y)) << (16 * j);
    }
    *(uint64_t*)(XRh + (size_t)prow * 1024 + c0) = wh;
  } else {
    const int wb = bid - 2048;               // 0..3071
    const int which = wb >> 10;
    const int i = (wb & 1023) * 256 + t;     // float4 index
    const float* src = (which == 0) ? Wk : (which == 1) ? Wv : Wp;
    const float4 v = ((const float4*)src)[i];
    const float vv[4] = { v.x, v.y, v.z, v.w };
    uint64_t wh = 0;
#pragma unroll
    for (int j = 0; j < 4; ++j)
      wh |= ((uint64_t)f2bf(vv[j])) << (16 * j);
    if (which == 2) {
      ((uint64_t*)Wph)[i] = wh;
    } else {
      ((uint64_t*)Wkvh)[(size_t)which * (1024 * 1024 / 4) + i] = wh;
    }
  }
}

// ---------------------------------------------------------------------------
// NT GEMM — r2 champion geometry (single LDS buffer, BK=128) + r6 reorder:
// per kt: sync (drains prev staging) -> ds_read ALL fragments to registers
// -> sync (lgkm drained; LDS now dead) -> STAGE(kt+1) into the SAME buffer
// -> MFMA phase on registers.  The wait for kt+1's loads (next iteration's
// first sync) lands AFTER the full BK=128 MFMA phase (~620cy/SIMD cover);
// r3's dbuf failed because its cover was only a BK=64 phase.
// C[m,n] = sum_k A[m,k]*B[n,k].
//   SMALLM=false: BM=128, waves 2x2, acc[4][4], LDS 64KB -> 2 blocks/CU.
//   SMALLM=true : BM=64,  waves 1x4, acc[4][2], LDS 48KB.
// LDS row = 256B (16 x 16B slots); phys slot s at row r holds src slot
// s ^ (r&7); ds_read same involution -> conflict-free (r2 measured).
// EPI: 0 = fp32 C32, 1 = bf16 hi Cb0, 2 = fp32 C32 + bias
// BATCHB: B advances N*K per rows_per_batch rows of A. AMODA: A row &1023.
// KSPLIT2: blockIdx.y in {0,1} selects K-half; C32/Cb0 += y*M*N.
// ---------------------------------------------------------------------------
template<bool BATCHB, bool AMODA, int EPI, bool KSPLIT2, bool SMALLM>
__global__ __launch_bounds__(256, 2)
void gemm_nt(const uint16_t* __restrict__ A0,
             const uint16_t* __restrict__ B0,
             float* __restrict__ C32, uint16_t* __restrict__ Cb0,
             const float* __restrict__ bias,
             int M, int N, int K, int rows_per_batch)
{
  constexpr int BM = SMALLM ? 64 : 128, BN = 128, BK = 128;
  constexpr int WCN = SMALLM ? 4 : 2;         // waves along N
  constexpr int WNW = BN / WCN;               // per-wave N width (32 or 64)
  constexpr int NREP = WNW / 16;              // 2 or 4
  constexpr int APASS = SMALLM ? 4 : 8;       // A staging passes (4KB each)
  constexpr int BPASS = 8;                    // B staging passes
  __shared__ uint16_t sA[BM * BK];
  __shared__ uint16_t sB[BN * BK];

  const int t = threadIdx.x;
  const int lane = t & 63;
  const int wave = t >> 6;
  const int wr = wave / WCN, wc = wave % WCN;
  const int fq = lane >> 4, fr = lane & 15;

  // T1: XCD-chunked swizzle (gridDim.x divisible by 8 for all our grids)
  const int nwg = gridDim.x;
  const int cpx = nwg >> 3;
  const int orig = blockIdx.x;
  const int swz = (orig & 7) * cpx + (orig >> 3);
  const int nbx = N >> 7;
  const int bm = (swz / nbx) * BM;
  const int bn = (swz % nbx) * BN;

  const uint16_t* Ap = A0;
  const uint16_t* Bp = B0;
  if (BATCHB)
    Bp += (size_t)(bm / rows_per_batch) * (size_t)N * (size_t)K;
  if (KSPLIT2) {
    const size_t half = (size_t)blockIdx.y * M * N;
    if (EPI == 1) Cb0 += half; else C32 += half;
  }

  f32x4 acc[4][NREP];
#pragma unroll
  for (int m = 0; m < 4; ++m)
#pragma unroll
    for (int n = 0; n < NREP; ++n) acc[m][n] = (f32x4)0.0f;

  auto STAGE = [&](int kt) {
#pragma unroll
    for (int i = 0; i < APASS; ++i) {
      const int X = t * 16 + i * 4096;          // linear LDS byte dest
      const int r = X >> 8;                     // row (256B per row)
      const int g = ((X >> 4) & 15) ^ (r & 7);  // pre-swizzled source slot
      const int kcol = (kt << 7) + g * 8;
      const int arow = AMODA ? ((bm + r) & 1023) : (bm + r);
      gload_lds16(Ap + (size_t)arow * K + kcol, (char*)(&sA[0]) + X);
    }
#pragma unroll
    for (int i = 0; i < BPASS; ++i) {
      const int X = t * 16 + i * 4096;
      const int r = X >> 8;
      const int g = ((X >> 4) & 15) ^ (r & 7);
      const int kcol = (kt << 7) + g * 8;
      gload_lds16(Bp + (size_t)(bn + r) * K + kcol, (char*)(&sB[0]) + X);
    }
  };

  const int nkt = K >> (KSPLIT2 ? 8 : 7);
  const int kt0 = KSPLIT2 ? (blockIdx.y * nkt) : 0;
  const int ktend = kt0 + nkt;

  STAGE(kt0);                                  // prologue prefetch
  for (int kt = kt0; kt < ktend; ++kt) {
    // drains this wave's staging loads (vmcnt 0) + barrier: tile kt ready.
    // Cover for those loads = previous iteration's MFMA phase.
    __syncthreads();

    // front-load the whole tile's fragments into registers
    s16x8 av[4][4], bv[4][NREP];               // [ks][.]
#pragma unroll
    for (int ks = 0; ks < 4; ++ks) {
#pragma unroll
      for (int m = 0; m < 4; ++m) {
        const int ra = wr * 64 + m * 16 + fr;
        const int offA = ra * 256 + ((((ks << 2) + fq) ^ (ra & 7)) << 4);
        av[ks][m] = *(const s16x8*)((const char*)(&sA[0]) + offA);
      }
#pragma unroll
      for (int n = 0; n < NREP; ++n) {
        const int rb = wc * WNW + n * 16 + fr;
        const int offB = rb * 256 + ((((ks << 2) + fq) ^ (rb & 7)) << 4);
        bv[ks][n] = *(const s16x8*)((const char*)(&sB[0]) + offB);
      }
    }

    // lgkm drained by syncthreads; after the barrier the LDS buffer is
    // dead (all waves hold their fragments) -> overwrite it early
    __syncthreads();
    if (kt + 1 < ktend) STAGE(kt + 1);

    // MFMA phase on registers (the latency cover for kt+1's loads)
#pragma unroll
    for (int ks = 0; ks < 4; ++ks)
#pragma unroll
      for (int m = 0; m < 4; ++m)
#pragma unroll
        for (int n = 0; n < NREP; ++n)
          acc[m][n] = __builtin_amdgcn_mfma_f32_16x16x32_bf16(
              av[ks][m], bv[ks][n], acc[m][n], 0, 0, 0);
  }

  // epilogue: C/D layout col = lane&15, row = (lane>>4)*4 + reg (m89/m91)
#pragma unroll
  for (int m = 0; m < 4; ++m) {
#pragma unroll
    for (int n = 0; n < NREP; ++n) {
#pragma unroll
      for (int j = 0; j < 4; ++j) {
        const int row = bm + wr * 64 + m * 16 + fq * 4 + j;
        const int col = bn + wc * WNW + n * 16 + fr;
        const size_t idx = (size_t)row * N + col;
        float v = acc[m][n][j];
        if constexpr (EPI == 0) {
          C32[idx] = v;
        } else if constexpr (EPI == 1) {
          Cb0[idx] = f2bf(v);
        } else {
          C32[idx] = v + bias[col];
        }
      }
    }
  }
}

// ---------------------------------------------------------------------------
// kv stage 1: partial[bid][f][e] = sum over 64 rows of K[.,f]*V[.,e].
// KVcat is bf16 in TWO split-K halves (stride 2048*2048); sum on stage (fp32).
// bid = bh*8 + ch. 1024 blocks -> full CU coverage.
// ---------------------------------------------------------------------------
__global__ __launch_bounds__(256)
void kv1_kernel(const uint16_t* __restrict__ KVcat, float* __restrict__ part)
{
  const int bid = blockIdx.x;
  const int bh = bid >> 3, ch = bid & 7;
  const int b = bh >> 5, h = bh & 31;
  const int t = threadIdx.x;
  __shared__ float sK[64][32];
  __shared__ float sV[64][32];
  const int f = t >> 3, e0 = (t & 7) * 4;
  const int lr = t >> 2, q = t & 3;
  const size_t rowb = (size_t)(b * 512 + ch * 64 + lr) * 2048 + h * 32 + q * 8;
  const size_t H = (size_t)2048 * 2048;   // second split-K half offset
  const s16x8 k0 = *(const s16x8*)(KVcat + rowb);
  const s16x8 k1 = *(const s16x8*)(KVcat + H + rowb);
  const s16x8 v0 = *(const s16x8*)(KVcat + rowb + 1024);
  const s16x8 v1 = *(const s16x8*)(KVcat + H + rowb + 1024);
#pragma unroll
  for (int j = 0; j < 8; ++j) {
    sK[lr][q * 8 + j] = bf2f((uint16_t)k0[j]) + bf2f((uint16_t)k1[j]);
    sV[lr][q * 8 + j] = bf2f((uint16_t)v0[j]) + bf2f((uint16_t)v1[j]);
  }
  __syncthreads();
  float a0 = 0.f, a1 = 0.f, a2 = 0.f, a3 = 0.f;
#pragma unroll 16
  for (int mm = 0; mm < 64; ++mm) {
    const float kf = sK[mm][f];
    const float4 vv = *(const float4*)&sV[mm][e0];
    a0 += kf * vv.x; a1 += kf * vv.y; a2 += kf * vv.z; a3 += kf * vv.w;
  }
  float* o = part + ((size_t)bid * 32 + f) * 32 + e0;
  o[0] = a0; o[1] = a1; o[2] = a2; o[3] = a3;
}

// ---------------------------------------------------------------------------
// t_kernel (kv2 fused): KV[b,h] = scale * sum_ch part[bh*8+ch];
// Tt[b][c][h*32+e] = sum_f KV[b,h][f,e] * Wq[h*32+f, c]   (bf16 hi out)
// grid: 512 blocks = (b, h, c-chunk of 256); 256 threads = one c each.
// ---------------------------------------------------------------------------
__global__ __launch_bounds__(256)
void t_kernel(const float* __restrict__ part, const float* __restrict__ Wq,
              uint16_t* __restrict__ Tth)
{
  const int bid = blockIdx.x;        // b*128 + h*4 + cc
  const int b = bid >> 7, h = (bid >> 2) & 31, cc = bid & 3;
  const int bh = b * 32 + h;
  const int t = threadIdx.x;
  __shared__ float sKV[32][32];      // [f][e]
  {
    const int f = t >> 3, e0 = (t & 7) * 4;
    f32x4 a = (f32x4)0.0f;
#pragma unroll
    for (int ch = 0; ch < 8; ++ch)
      a += *(const f32x4*)(part + ((size_t)(bh * 8 + ch) * 32 + f) * 32 + e0);
    a *= 0.17677669529663687f;       // 1/sqrt(32)
    *(f32x4*)&sKV[f][e0] = a;
  }
  __syncthreads();
  const int c = cc * 256 + t;
  f32x4 acc[8];
#pragma unroll
  for (int i = 0; i < 8; ++i) acc[i] = (f32x4)0.0f;
  const float* wqp = Wq + (size_t)(h * 32) * 1024 + c;
#pragma unroll 8
  for (int f = 0; f < 32; ++f) {
    const float wq = wqp[(size_t)f * 1024];
#pragma unroll
    for (int i = 0; i < 8; ++i) {
      const f32x4 kv = *(const f32x4*)&sKV[f][i * 4];
      acc[i] += kv * wq;
    }
  }
  const size_t o = (((size_t)b << 10) + c) * 1024 + h * 32;
#pragma unroll
  for (int i = 0; i < 8; ++i) {
    uint64_t wh = 0;
#pragma unroll
    for (int j = 0; j < 4; ++j)
      wh |= ((uint64_t)f2bf(acc[i][j])) << (16 * j);
    *(uint64_t*)(Tth + o + i * 4) = wh;
  }
}

// ---------------------------------------------------------------------------
extern "C" void kernel_launch(void* const* d_in, const int* in_sizes, int n_in,
                              void* d_out, int out_size, void* d_ws, size_t ws_size,
                              hipStream_t stream)
{
  const float* x   = (const float*)d_in[0];
  const float* Wq  = (const float*)d_in[1];
  const float* Wk  = (const float*)d_in[2];
  const float* Wv  = (const float*)d_in[3];
  const float* Wp  = (const float*)d_in[4];
  const float* bp  = (const float*)d_in[5];
  const float* bng = (const float*)d_in[6];
  const float* bnb = (const float*)d_in[7];
  const float* bnm = (const float*)d_in[8];
  const float* bnv = (const float*)d_in[9];
  float* out = (float*)d_out;

  char* ws = (char*)d_ws;
  size_t off = 0;
  auto alloc = [&](size_t bytes) {
    char* p = ws + off;
    off += (bytes + 255) & ~(size_t)255;
    return p;
  };
  uint16_t* Xh   = (uint16_t*)alloc((size_t)8192 * 1024 * 2);       // 16MB
  uint16_t* XRh  = (uint16_t*)alloc((size_t)2048 * 1024 * 2);       // 4MB
  uint16_t* Wkvh = (uint16_t*)alloc((size_t)2048 * 1024 * 2);       // 4MB
  uint16_t* Wph  = (uint16_t*)alloc((size_t)1024 * 1024 * 2);       // 2MB
  uint16_t* KVcat= (uint16_t*)alloc((size_t)2 * 2048 * 2048 * 2);   // 16MB (2 bf16 halves)
  uint16_t* Gh   = (uint16_t*)alloc((size_t)4096 * 1024 * 2);       // 8MB
  // overlays (lifetime-disjoint):
  // KVcat dead after kv1 -> Tth (8MB = first half)
  uint16_t* Tth = KVcat;
  // kv partials (4MB) live only kv1 -> t_kernel, before G-GEMM writes Gh
  float* KVpart = (float*)Gh;

  // 1) fused prep: x split (hi) + XR pool/BN (hi) + weight splits (hi)
  prep_kernel<<<5120, 256, 0, stream>>>(x, bng, bnb, bnm, bnv, Wk, Wv, Wp,
                                        Xh, XRh, Wkvh, Wph);
  // 2) [K|V] = XRh @ [Wk;Wv]h^T (hh only), split-K x2, bf16 partial halves
  gemm_nt<false, false, 1, true, false><<<dim3(256, 2), 256, 0, stream>>>(
      XRh, Wkvh, nullptr, KVcat, nullptr,
      2048, 2048, 1024, 1 << 30);
  // 3) KV partials (sums the two bf16 split-K halves while staging)
  kv1_kernel<<<1024, 256, 0, stream>>>(KVcat, KVpart);
  // 4) Tt = (blockdiag(KV)^T Wq)^T, bf16 hi (kv2 fused; overlays KVcat)
  t_kernel<<<512, 256, 0, stream>>>(KVpart, Wq, Tth);
  // 5) G[b] = Wph @ Tt[b]^T (hh only), bf16 out, BM=64 -> 512 blocks (2/CU)
  gemm_nt<true, true, 1, false, true><<<512, 256, 0, stream>>>(
      Wph, Tth, nullptr, Gh, nullptr,
      4096, 1024, 1024, 1024);
  // 6) out = Xh @ G[b]^T + bp (hh only), fp32 out
  gemm_nt<true, false, 2, false, false><<<512, 256, 0, stream>>>(
      Xh, Gh, out, nullptr, bp,
      8192, 1024, 1024, 2048);
}